// Round 1
// baseline (966.853 us; speedup 1.0000x reference)
//
#include <hip/hip_runtime.h>

// One wave (64 lanes) per sample; lane = output channel of conv2.
// 4 samples per 256-thread block share one LDS copy of w2 (53 KB).
// All LIF state in registers; spk1 floats staged per-wave in LDS.

#define SPB 4                    // samples per block (one wave each)
#define THREADS (SPB * 64)
#define NSTEPS 100

__global__ __launch_bounds__(THREADS, 2)
void snn_kernel(const float* __restrict__ x,
                const float* __restrict__ w1,
                const float* __restrict__ b1,
                const float* __restrict__ w2,
                const float* __restrict__ b2,
                const float* __restrict__ wf,
                const float* __restrict__ bf,
                float* __restrict__ out,
                int B)
{
    // LDS: w2 [64][208] (natural layout: k = ic*16+ky*4+kx), small tables,
    // per-sample spike buffer (also reused as x staging at init).
    __shared__ __align__(16) float s_w2[64 * 208];
    __shared__ __align__(16) float s_w1[13 * 16];
    __shared__ float s_b1[16];
    __shared__ float s_b2[64];
    __shared__ __align__(16) float s_spk[SPB][468];   // 468*4B = 1872B, 16B-mult row stride

    const int tid  = threadIdx.x;
    const int wave = tid >> 6;
    const int lane = tid & 63;
    const int oc   = lane;
    const int s    = blockIdx.x * SPB + wave;

    // ---- stage weights (block-wide) ----
    for (int i = tid; i < (64 * 208) / 4; i += THREADS)
        ((float4*)s_w2)[i] = ((const float4*)w2)[i];
    for (int i = tid; i < (13 * 16) / 4; i += THREADS)
        ((float4*)s_w1)[i] = ((const float4*)w1)[i];
    if (tid < 13) s_b1[tid] = b1[tid];
    if (tid < 64) s_b2[tid] = b2[tid];

    // ---- stage this sample's input image into the spike buffer (256 floats) ----
    ((float4*)&s_spk[wave][0])[lane] = ((const float4*)(x + (size_t)s * 256))[lane];
    __syncthreads();

    // ---- cur1 = maxpool2(conv1(x)+b1): [13][6][6]; thread owns e = lane+64j ----
    float cur1[8], v1[8], i1[8];
    {
        const float* xl = &s_spk[wave][0];
        #pragma unroll
        for (int j = 0; j < 8; ++j) {
            v1[j] = 0.f; i1[j] = 0.f; cur1[j] = 0.f;
            const int e = lane + 64 * j;
            if (e < 468) {
                const int ic = e / 36, r = e % 36, py = r / 6, px = r % 6;
                float m = -1e30f;
                #pragma unroll
                for (int dy = 0; dy < 2; ++dy)
                #pragma unroll
                for (int dx = 0; dx < 2; ++dx) {
                    const int cy = 2 * py + dy, cx = 2 * px + dx;
                    float a = 0.f;
                    #pragma unroll
                    for (int ky = 0; ky < 4; ++ky)
                    #pragma unroll
                    for (int kx = 0; kx < 4; ++kx)
                        a = fmaf(xl[(cy + ky) * 16 + cx + kx],
                                 s_w1[ic * 16 + ky * 4 + kx], a);
                    a += s_b1[ic];
                    m = fmaxf(m, a);
                }
                cur1[j] = m;
            }
        }
    }
    __syncthreads();   // done reading x from the spike buffer

    // ---- static per-lane data in registers ----
    float wf0[9], wf1[9];
    #pragma unroll
    for (int p = 0; p < 9; ++p) {
        wf0[p] = wf[oc * 9 + p];
        wf1[p] = wf[576 + oc * 9 + p];
    }
    const float bf0 = bf[0], bf1 = bf[1];
    const float b2o = s_b2[oc];

    float v2[9], i2[9];
    #pragma unroll
    for (int p = 0; p < 9; ++p) { v2[p] = 0.f; i2[p] = 0.f; }
    float v3a = 0.f, i3a = 0.f, v3b = 0.f, i3b = 0.f;
    float sum0 = 0.f, sum1 = 0.f;

    float* outv = out + (size_t)2 * B;   // v3_seq base (after spk_out [B][2])

    for (int t = 0; t < NSTEPS; ++t) {
        // ---- LIF1: update state, write spikes (floats) to LDS ----
        #pragma unroll
        for (int j = 0; j < 8; ++j) {
            const float vd = v1[j] + 0.1f * (i1[j] - v1[j]);
            i1[j] = i1[j] * 0.8f + cur1[j];
            const float z = (vd > 1.0f) ? 1.0f : 0.0f;
            v1[j] = (vd > 1.0f) ? 0.0f : vd;
            const int e = lane + 64 * j;
            if (e < 468) s_spk[wave][e] = z;
        }
        __syncthreads();

        // ---- conv2: acc[pos] += spk[ic][y+ky][x+kx] * w2[oc][ic][ky][kx] ----
        float acc[9];
        #pragma unroll
        for (int p = 0; p < 9; ++p) acc[p] = 0.f;
        {
            const float* sp = &s_spk[wave][0];
            for (int ic = 0; ic < 13; ++ic) {
                float sv[36];
                #pragma unroll
                for (int q = 0; q < 9; ++q) {
                    const float4 t4 = ((const float4*)(sp + ic * 36))[q];
                    sv[4 * q + 0] = t4.x; sv[4 * q + 1] = t4.y;
                    sv[4 * q + 2] = t4.z; sv[4 * q + 3] = t4.w;
                }
                float wv[16];
                #pragma unroll
                for (int q = 0; q < 4; ++q) {
                    const float4 t4 = ((const float4*)(s_w2 + oc * 208 + ic * 16))[q];
                    wv[4 * q + 0] = t4.x; wv[4 * q + 1] = t4.y;
                    wv[4 * q + 2] = t4.z; wv[4 * q + 3] = t4.w;
                }
                #pragma unroll
                for (int ky = 0; ky < 4; ++ky)
                #pragma unroll
                for (int kx = 0; kx < 4; ++kx) {
                    const float w = wv[ky * 4 + kx];
                    #pragma unroll
                    for (int yy = 0; yy < 3; ++yy)
                    #pragma unroll
                    for (int xx = 0; xx < 3; ++xx)
                        acc[yy * 3 + xx] =
                            fmaf(sv[(yy + ky) * 6 + xx + kx], w, acc[yy * 3 + xx]);
                }
            }
        }
        __syncthreads();

        // ---- LIF2 + fc partials (lane covers oc; 9 positions each) ----
        float p0 = 0.f, p1 = 0.f;
        #pragma unroll
        for (int p = 0; p < 9; ++p) {
            const float c2 = acc[p] + b2o;
            const float vd = v2[p] + 0.1f * (i2[p] - v2[p]);
            i2[p] = i2[p] * 0.8f + c2;
            const float z = (vd > 1.0f) ? 1.0f : 0.0f;
            v2[p] = (vd > 1.0f) ? 0.0f : vd;
            p0 = fmaf(z, wf0[p], p0);
            p1 = fmaf(z, wf1[p], p1);
        }
        // wave-wide reduction (64 lanes)
        #pragma unroll
        for (int off = 32; off > 0; off >>= 1) {
            p0 += __shfl_xor(p0, off);
            p1 += __shfl_xor(p1, off);
        }

        // ---- LIF3 (uniform across lanes) ----
        const float c0 = p0 + bf0, c1 = p1 + bf1;
        const float vd0 = v3a + 0.1f * (i3a - v3a);
        const float vd1 = v3b + 0.1f * (i3b - v3b);
        i3a = i3a * 0.8f + c0;
        i3b = i3b * 0.8f + c1;
        const float z0 = (vd0 > 1.0f) ? 1.0f : 0.0f;
        const float z1 = (vd1 > 1.0f) ? 1.0f : 0.0f;
        v3a = (vd0 > 1.0f) ? 0.0f : vd0;
        v3b = (vd1 > 1.0f) ? 0.0f : vd1;
        sum0 += z0; sum1 += z1;

        if (lane == 0) {
            *(float2*)(outv + (size_t)t * 2 * B + 2 * s) = make_float2(v3a, v3b);
        }
    }

    if (lane == 0) {
        *(float2*)(out + (size_t)2 * s) = make_float2(sum0, sum1);
    }
}

extern "C" void kernel_launch(void* const* d_in, const int* in_sizes, int n_in,
                              void* d_out, int out_size, void* d_ws, size_t ws_size,
                              hipStream_t stream)
{
    const float* x  = (const float*)d_in[0];
    const float* w1 = (const float*)d_in[1];
    const float* b1 = (const float*)d_in[2];
    const float* w2 = (const float*)d_in[3];
    const float* b2 = (const float*)d_in[4];
    const float* wf = (const float*)d_in[5];
    const float* bf = (const float*)d_in[6];
    float* out = (float*)d_out;

    const int B = in_sizes[0] / 256;     // x is [B,1,16,16]
    const int grid = B / SPB;            // B=2048 -> 512 blocks

    hipLaunchKernelGGL(snn_kernel, dim3(grid), dim3(THREADS), 0, stream,
                       x, w1, b1, w2, b2, wf, bf, out, B);
}

// Round 2
// 847.103 us; speedup vs baseline: 1.1414x; 1.1414x over previous
//
#include <hip/hip_runtime.h>

// One wave (64 lanes) per sample; lane = output channel of conv2.
// 4 samples per 256-thread block share one LDS copy of w2 (53 KB).
// All LIF state in registers; spk1 floats staged per-wave in LDS.
//
// R2 changes vs R1:
//  - w2 repacked in LDS as [ic*4+q][oc] float4 -> lane-consecutive b128
//    reads, conflict-free (R1 had oc*208 word stride -> 32-way conflicts,
//    1.3e8 conflict cycles = ~21% of runtime).
//  - per-step __syncthreads() removed: s_spk rows are wave-private, the
//    in-order LDS pipe + compiler lgkmcnt ordering make barriers redundant.
//  - spike rows padded to 512 so LIF1 stores are unconditional.

#define SPB 4                    // samples per block (one wave each)
#define THREADS (SPB * 64)
#define NSTEPS 100

__global__ __launch_bounds__(THREADS, 2)
void snn_kernel(const float* __restrict__ x,
                const float* __restrict__ w1,
                const float* __restrict__ b1,
                const float* __restrict__ w2,
                const float* __restrict__ b2,
                const float* __restrict__ wf,
                const float* __restrict__ bf,
                float* __restrict__ out,
                int B)
{
    // w2 transposed: float4 chunk q of (oc, ic) lives at s_w2q[(ic*4+q)*64 + oc]
    __shared__ __align__(16) float4 s_w2q[13 * 4 * 64];   // 53248 B
    __shared__ __align__(16) float s_w1[13 * 16];
    __shared__ float s_b1[16];
    __shared__ float s_b2[64];
    __shared__ __align__(16) float s_spk[SPB][512];       // padded: unconditional writes

    const int tid  = threadIdx.x;
    const int wave = tid >> 6;
    const int lane = tid & 63;
    const int oc   = lane;
    const int s    = blockIdx.x * SPB + wave;

    // ---- stage weights (block-wide) ----
    // w2 flat: [oc][ic][ky][kx] = [oc][k], k = ic*16+ky*4+kx; as float4: i = oc*52 + r,
    // r = ic*4+q. Transposed LDS slot: r*64 + oc.
    for (int i = tid; i < 64 * 52; i += THREADS) {
        const float4 v = ((const float4*)w2)[i];
        const int ocx = i / 52, r = i % 52;
        s_w2q[r * 64 + ocx] = v;
    }
    for (int i = tid; i < (13 * 16) / 4; i += THREADS)
        ((float4*)s_w1)[i] = ((const float4*)w1)[i];
    if (tid < 13) s_b1[tid] = b1[tid];
    if (tid < 64) s_b2[tid] = b2[tid];

    // ---- stage this sample's input image into the spike buffer (256 floats) ----
    ((float4*)&s_spk[wave][0])[lane] = ((const float4*)(x + (size_t)s * 256))[lane];
    __syncthreads();

    // ---- cur1 = maxpool2(conv1(x)+b1): [13][6][6]; thread owns e = lane+64j ----
    float cur1[8], v1[8], i1[8];
    {
        const float* xl = &s_spk[wave][0];
        #pragma unroll
        for (int j = 0; j < 8; ++j) {
            v1[j] = 0.f; i1[j] = 0.f; cur1[j] = 0.f;
            const int e = lane + 64 * j;
            if (e < 468) {
                const int ic = e / 36, r = e % 36, py = r / 6, px = r % 6;
                float m = -1e30f;
                #pragma unroll
                for (int dy = 0; dy < 2; ++dy)
                #pragma unroll
                for (int dx = 0; dx < 2; ++dx) {
                    const int cy = 2 * py + dy, cx = 2 * px + dx;
                    float a = 0.f;
                    #pragma unroll
                    for (int ky = 0; ky < 4; ++ky)
                    #pragma unroll
                    for (int kx = 0; kx < 4; ++kx)
                        a = fmaf(xl[(cy + ky) * 16 + cx + kx],
                                 s_w1[ic * 16 + ky * 4 + kx], a);
                    a += s_b1[ic];
                    m = fmaxf(m, a);
                }
                cur1[j] = m;
            }
        }
    }
    // conv1 read s_spk (x image); LIF1 below overwrites it. Wave-local WAR:
    // in-order LDS pipe handles it; fence stops compiler migration only.
    __builtin_amdgcn_wave_barrier();

    // ---- static per-lane data in registers ----
    float wf0[9], wf1[9];
    #pragma unroll
    for (int p = 0; p < 9; ++p) {
        wf0[p] = wf[oc * 9 + p];
        wf1[p] = wf[576 + oc * 9 + p];
    }
    const float bf0 = bf[0], bf1 = bf[1];
    const float b2o = s_b2[oc];

    float v2[9], i2[9];
    #pragma unroll
    for (int p = 0; p < 9; ++p) { v2[p] = 0.f; i2[p] = 0.f; }
    float v3a = 0.f, i3a = 0.f, v3b = 0.f, i3b = 0.f;
    float sum0 = 0.f, sum1 = 0.f;

    float* outv = out + (size_t)2 * B;   // v3_seq base (after spk_out [B][2])

    for (int t = 0; t < NSTEPS; ++t) {
        // ---- LIF1: update state, write spikes (floats) to wave-private LDS ----
        #pragma unroll
        for (int j = 0; j < 8; ++j) {
            const float vd = v1[j] + 0.1f * (i1[j] - v1[j]);
            i1[j] = i1[j] * 0.8f + cur1[j];
            const float z = (vd > 1.0f) ? 1.0f : 0.0f;
            v1[j] = (vd > 1.0f) ? 0.0f : vd;
            s_spk[wave][lane + 64 * j] = z;   // rows padded to 512: no bounds check
        }
        __builtin_amdgcn_wave_barrier();

        // ---- conv2: acc[pos] += spk[ic][y+ky][x+kx] * w2[oc][ic][ky][kx] ----
        float acc[9];
        #pragma unroll
        for (int p = 0; p < 9; ++p) acc[p] = 0.f;
        {
            const float* sp = &s_spk[wave][0];
            for (int ic = 0; ic < 13; ++ic) {
                float sv[36];
                #pragma unroll
                for (int q = 0; q < 9; ++q) {
                    const float4 t4 = ((const float4*)(sp + ic * 36))[q];
                    sv[4 * q + 0] = t4.x; sv[4 * q + 1] = t4.y;
                    sv[4 * q + 2] = t4.z; sv[4 * q + 3] = t4.w;
                }
                float wv[16];
                #pragma unroll
                for (int q = 0; q < 4; ++q) {
                    const float4 t4 = s_w2q[(ic * 4 + q) * 64 + oc];
                    wv[4 * q + 0] = t4.x; wv[4 * q + 1] = t4.y;
                    wv[4 * q + 2] = t4.z; wv[4 * q + 3] = t4.w;
                }
                #pragma unroll
                for (int ky = 0; ky < 4; ++ky)
                #pragma unroll
                for (int kx = 0; kx < 4; ++kx) {
                    const float w = wv[ky * 4 + kx];
                    #pragma unroll
                    for (int yy = 0; yy < 3; ++yy)
                    #pragma unroll
                    for (int xx = 0; xx < 3; ++xx)
                        acc[yy * 3 + xx] =
                            fmaf(sv[(yy + ky) * 6 + xx + kx], w, acc[yy * 3 + xx]);
                }
            }
        }
        __builtin_amdgcn_wave_barrier();

        // ---- LIF2 + fc partials (lane covers oc; 9 positions each) ----
        float p0 = 0.f, p1 = 0.f;
        #pragma unroll
        for (int p = 0; p < 9; ++p) {
            const float c2 = acc[p] + b2o;
            const float vd = v2[p] + 0.1f * (i2[p] - v2[p]);
            i2[p] = i2[p] * 0.8f + c2;
            const float z = (vd > 1.0f) ? 1.0f : 0.0f;
            v2[p] = (vd > 1.0f) ? 0.0f : vd;
            p0 = fmaf(z, wf0[p], p0);
            p1 = fmaf(z, wf1[p], p1);
        }
        // wave-wide reduction (64 lanes)
        #pragma unroll
        for (int off = 32; off > 0; off >>= 1) {
            p0 += __shfl_xor(p0, off);
            p1 += __shfl_xor(p1, off);
        }

        // ---- LIF3 (uniform across lanes) ----
        const float c0 = p0 + bf0, c1 = p1 + bf1;
        const float vd0 = v3a + 0.1f * (i3a - v3a);
        const float vd1 = v3b + 0.1f * (i3b - v3b);
        i3a = i3a * 0.8f + c0;
        i3b = i3b * 0.8f + c1;
        const float z0 = (vd0 > 1.0f) ? 1.0f : 0.0f;
        const float z1 = (vd1 > 1.0f) ? 1.0f : 0.0f;
        v3a = (vd0 > 1.0f) ? 0.0f : vd0;
        v3b = (vd1 > 1.0f) ? 0.0f : vd1;
        sum0 += z0; sum1 += z1;

        if (lane == 0) {
            *(float2*)(outv + (size_t)t * 2 * B + 2 * s) = make_float2(v3a, v3b);
        }
    }

    if (lane == 0) {
        *(float2*)(out + (size_t)2 * s) = make_float2(sum0, sum1);
    }
}

extern "C" void kernel_launch(void* const* d_in, const int* in_sizes, int n_in,
                              void* d_out, int out_size, void* d_ws, size_t ws_size,
                              hipStream_t stream)
{
    const float* x  = (const float*)d_in[0];
    const float* w1 = (const float*)d_in[1];
    const float* b1 = (const float*)d_in[2];
    const float* w2 = (const float*)d_in[3];
    const float* b2 = (const float*)d_in[4];
    const float* wf = (const float*)d_in[5];
    const float* bf = (const float*)d_in[6];
    float* out = (float*)d_out;

    const int B = in_sizes[0] / 256;     // x is [B,1,16,16]
    const int grid = B / SPB;            // B=2048 -> 512 blocks

    hipLaunchKernelGGL(snn_kernel, dim3(grid), dim3(THREADS), 0, stream,
                       x, w1, b1, w2, b2, wf, bf, out, B);
}

// Round 3
// 304.486 us; speedup vs baseline: 3.1754x; 2.7821x over previous
//
#include <hip/hip_runtime.h>

// MFMA rewrite: conv2 as C[64oc x 36(s,pos)] = W[64x208] * im2col(spk)[208x36].
// Block = 256 thr = 4 waves = 4 samples. Wave w: M-tile oc[16w..16w+15], all 3
// N-tiles, K padded to 224 (7 K-tiles of 32). Weights in 3-way bf16 split
// (hi+mid+lo, exact fp32 residuals -> ~2^-24 relative error, fp32-grade).
// Spikes are exact in bf16. LIF1 writes bf16 quads directly into the im2col
// LDS buffer; LIF2 state lives in MFMA C-layout registers; fc per-wave.
// Verified layouts (learn_hip m89/m91/m120):
//   A[m][k]: m=lane&15, k=(lane>>4)*8+j   (j = element 0..7 of short8)
//   B[k][n]: n=lane&15, k=(lane>>4)*8+j
//   C/D   : col=lane&15, row=(lane>>4)*4+reg

#define NSTEPS 100
#define IMSTRIDE 464   // bytes per im2col row; 116 words == 20 mod 32 banks (2-way max)

typedef __attribute__((ext_vector_type(8))) short bf16x8;
typedef __attribute__((ext_vector_type(4))) float f32x4;

__device__ __forceinline__ unsigned short f2bf(float f) {
    unsigned u = __float_as_uint(f);
    unsigned r = ((u >> 16) & 1u) + 0x7FFFu;
    return (unsigned short)((u + r) >> 16);
}
__device__ __forceinline__ float bf2f(unsigned short h) {
    return __uint_as_float(((unsigned)h) << 16);
}

// conv1 + 2x2 maxpool for one spike-row (sample, ic, y): 6 outputs
__device__ __forceinline__ void conv1_row(const float* __restrict__ xs,
                                          const float* __restrict__ w1s,
                                          float b1v, int y, float* cur) {
    float cr[2][12];
    #pragma unroll
    for (int rr = 0; rr < 2; ++rr) {
        const int cy = 2 * y + rr;
        #pragma unroll
        for (int cx = 0; cx < 12; ++cx) {
            float a = 0.f;
            #pragma unroll
            for (int ky = 0; ky < 4; ++ky)
            #pragma unroll
            for (int kx = 0; kx < 4; ++kx)
                a = fmaf(xs[(cy + ky) * 16 + cx + kx], w1s[ky * 4 + kx], a);
            cr[rr][cx] = a + b1v;
        }
    }
    #pragma unroll
    for (int px = 0; px < 6; ++px)
        cur[px] = fmaxf(fmaxf(cr[0][2 * px], cr[0][2 * px + 1]),
                        fmaxf(cr[1][2 * px], cr[1][2 * px + 1]));
}

// LIF1 for one spike-row + scatter bf16 quads into im2col rows
__device__ __forceinline__ void lif1_row(float* v1, float* i1, const float* cur,
                                         unsigned char* s_im, int sl, int ic, int y) {
    unsigned zb[6];
    #pragma unroll
    for (int xx = 0; xx < 6; ++xx) {
        const float vd = v1[xx] + 0.1f * (i1[xx] - v1[xx]);
        i1[xx] = i1[xx] * 0.8f + cur[xx];
        const bool sp = vd > 1.0f;
        v1[xx] = sp ? 0.0f : vd;
        zb[xx] = sp ? 0x3F80u : 0u;     // bf16 1.0 bits
    }
    const unsigned p0 = zb[0] | (zb[1] << 16);
    const unsigned p1 = zb[1] | (zb[2] << 16);
    const unsigned p2 = zb[2] | (zb[3] << 16);
    const unsigned p3 = zb[3] | (zb[4] << 16);
    const unsigned p4 = zb[4] | (zb[5] << 16);
    const uint2 q0 = make_uint2(p0, p2);   // z[0..3]
    const uint2 q1 = make_uint2(p1, p3);   // z[1..4]
    const uint2 q2 = make_uint2(p2, p4);   // z[2..5]
    unsigned char* rowk = s_im + ic * 32;
    #pragma unroll
    for (int ky = 0; ky < 4; ++ky) {
        const int py = y - ky;
        if (0 <= py && py <= 2) {
            unsigned char* b = rowk + (sl * 9 + py * 3) * IMSTRIDE + ky * 8;
            *(uint2*)(b) = q0;                    // px = 0
            *(uint2*)(b + IMSTRIDE) = q1;         // px = 1
            *(uint2*)(b + 2 * IMSTRIDE) = q2;     // px = 2
        }
    }
}

__global__ __launch_bounds__(256, 2)
void snn_kernel(const float* __restrict__ x,
                const float* __restrict__ w1,
                const float* __restrict__ b1,
                const float* __restrict__ w2,
                const float* __restrict__ b2,
                const float* __restrict__ wf,
                const float* __restrict__ bf,
                float* __restrict__ out, int B)
{
    __shared__ __align__(16) unsigned char s_im[48 * IMSTRIDE];  // 22272 B
    __shared__ __align__(16) float s_z2[4 * 576];                // 9216 B (also x scratch)
    __shared__ __align__(16) float s_w1[13 * 16];
    __shared__ float s_b1[13];

    const int tid  = threadIdx.x;
    const int wave = tid >> 6, lane = tid & 63;
    const int quad = lane >> 4, col = lane & 15;

    // ---- stage x (4 samples) into s_z2 scratch; stage w1/b1; zero im2col ----
    ((float4*)(s_z2 + wave * 256))[lane] =
        ((const float4*)(x + (size_t)(blockIdx.x * 4 + wave) * 256))[lane];
    if (tid < 208) s_w1[tid] = w1[tid];
    if (tid < 13)  s_b1[tid] = b1[tid];
    for (int i = tid; i < 48 * IMSTRIDE / 16; i += 256)
        ((uint4*)s_im)[i] = make_uint4(0, 0, 0, 0);
    __syncthreads();

    // ---- LIF1 row ownership: rows R = tid and tid+256 of 312 = 4*13*6 ----
    int sA, icA, yA, sB = 0, icB = 0, yB = 0;
    { const int R = tid;       sA = R / 78; int r = R - 78 * sA; icA = r / 6; yA = r - 6 * icA; }
    if (tid < 56) { const int R = tid + 256; sB = R / 78; int r = R - 78 * sB; icB = r / 6; yB = r - 6 * icB; }

    float cur1a[6], v1a[6], i1a[6], cur1b[6], v1b[6], i1b[6];
    conv1_row(s_z2 + sA * 256, s_w1 + icA * 16, s_b1[icA], yA, cur1a);
    if (tid < 56) conv1_row(s_z2 + sB * 256, s_w1 + icB * 16, s_b1[icB], yB, cur1b);
    #pragma unroll
    for (int j = 0; j < 6; ++j) { v1a[j] = i1a[j] = 0.f; v1b[j] = i1b[j] = 0.f; }

    // ---- A-fragments: 3-way bf16 split of w2 rows, static in registers ----
    bf16x8 Ahi[7], Amid[7], Alo[7];
    {
        const float* wrow = w2 + (size_t)(wave * 16 + col) * 208;
        #pragma unroll
        for (int kt = 0; kt < 7; ++kt) {
            const int k0 = kt * 32 + quad * 8;
            bf16x8 h, m, l;
            #pragma unroll
            for (int j = 0; j < 8; ++j) {
                const int k = k0 + j;
                const float w = (k < 208) ? wrow[k] : 0.f;
                const unsigned short hb = f2bf(w);  const float r1 = w - bf2f(hb);
                const unsigned short mb = f2bf(r1); const float r2 = r1 - bf2f(mb);
                const unsigned short lb = f2bf(r2);
                h[j] = (short)hb; m[j] = (short)mb; l[j] = (short)lb;
            }
            Ahi[kt] = h; Amid[kt] = m; Alo[kt] = l;
        }
    }

    // ---- static per-lane: fc weights, b2, B-frag ptrs, z2 write ptrs ----
    float wf0[9], wf1[9];
    #pragma unroll
    for (int q = 0; q < 9; ++q) { wf0[q] = wf[lane + 64 * q]; wf1[q] = wf[576 + lane + 64 * q]; }
    const float bf0 = bf[0], bf1 = bf[1];
    float b2r[4];
    #pragma unroll
    for (int r = 0; r < 4; ++r) b2r[r] = b2[wave * 16 + quad * 4 + r];

    const unsigned char* bp[3];
    float* zwp[3];
    bool zv[3];
    #pragma unroll
    for (int nt = 0; nt < 3; ++nt) {
        const int n = nt * 16 + col;
        bp[nt] = s_im + n * IMSTRIDE + quad * 16;
        zv[nt] = (n < 36);
        const int slz = n / 9, pos = n - slz * 9;
        zwp[nt] = s_z2 + slz * 576 + (wave * 16 + quad * 4) * 9 + pos;
    }

    float v2[12], i2[12];
    #pragma unroll
    for (int p = 0; p < 12; ++p) { v2[p] = 0.f; i2[p] = 0.f; }
    float v3a = 0.f, i3a = 0.f, v3b = 0.f, i3b = 0.f, sum0 = 0.f, sum1 = 0.f;

    const int sG = blockIdx.x * 4 + wave;
    float* outv = out + (size_t)2 * B;
    __syncthreads();

    #pragma unroll 1
    for (int t = 0; t < NSTEPS; ++t) {
        // ---- Phase A: LIF1 + im2col scatter ----
        lif1_row(v1a, i1a, cur1a, s_im, sA, icA, yA);
        if (tid < 56) lif1_row(v1b, i1b, cur1b, s_im, sB, icB, yB);
        __syncthreads();

        // ---- Phase B: MFMA, 3 interleaved acc chains ----
        f32x4 c0 = {0.f, 0.f, 0.f, 0.f}, c1 = c0, c2 = c0;
        #pragma unroll
        for (int kt = 0; kt < 7; ++kt) {
            const bf16x8 b0 = *(const bf16x8*)(bp[0] + kt * 64);
            const bf16x8 b1v = *(const bf16x8*)(bp[1] + kt * 64);
            const bf16x8 b2v = *(const bf16x8*)(bp[2] + kt * 64);
            c0 = __builtin_amdgcn_mfma_f32_16x16x32_bf16(Alo[kt],  b0,  c0, 0, 0, 0);
            c1 = __builtin_amdgcn_mfma_f32_16x16x32_bf16(Alo[kt],  b1v, c1, 0, 0, 0);
            c2 = __builtin_amdgcn_mfma_f32_16x16x32_bf16(Alo[kt],  b2v, c2, 0, 0, 0);
            c0 = __builtin_amdgcn_mfma_f32_16x16x32_bf16(Amid[kt], b0,  c0, 0, 0, 0);
            c1 = __builtin_amdgcn_mfma_f32_16x16x32_bf16(Amid[kt], b1v, c1, 0, 0, 0);
            c2 = __builtin_amdgcn_mfma_f32_16x16x32_bf16(Amid[kt], b2v, c2, 0, 0, 0);
            c0 = __builtin_amdgcn_mfma_f32_16x16x32_bf16(Ahi[kt],  b0,  c0, 0, 0, 0);
            c1 = __builtin_amdgcn_mfma_f32_16x16x32_bf16(Ahi[kt],  b1v, c1, 0, 0, 0);
            c2 = __builtin_amdgcn_mfma_f32_16x16x32_bf16(Ahi[kt],  b2v, c2, 0, 0, 0);
        }

        // ---- Phase B2: LIF2 + z2 export (C layout: row=quad*4+r, col) ----
        f32x4 cc[3] = {c0, c1, c2};
        #pragma unroll
        for (int nt = 0; nt < 3; ++nt) {
            #pragma unroll
            for (int r = 0; r < 4; ++r) {
                const int p = nt * 4 + r;
                const float cur2 = cc[nt][r] + b2r[r];
                const float vd = v2[p] + 0.1f * (i2[p] - v2[p]);
                i2[p] = i2[p] * 0.8f + cur2;
                const bool sp = vd > 1.0f;
                v2[p] = sp ? 0.0f : vd;
                if (zv[nt]) zwp[nt][9 * r] = sp ? 1.0f : 0.0f;
            }
        }
        __syncthreads();

        // ---- Phase C: fc + LIF3 (wave = its sample) ----
        const float* zs = s_z2 + wave * 576;
        float p0 = 0.f, p1 = 0.f;
        #pragma unroll
        for (int q = 0; q < 9; ++q) {
            const float z = zs[lane + 64 * q];
            p0 = fmaf(z, wf0[q], p0);
            p1 = fmaf(z, wf1[q], p1);
        }
        #pragma unroll
        for (int off = 32; off > 0; off >>= 1) {
            p0 += __shfl_xor(p0, off);
            p1 += __shfl_xor(p1, off);
        }
        const float c3a = p0 + bf0, c3b = p1 + bf1;
        const float vd0 = v3a + 0.1f * (i3a - v3a);
        const float vd1 = v3b + 0.1f * (i3b - v3b);
        i3a = i3a * 0.8f + c3a;
        i3b = i3b * 0.8f + c3b;
        const bool s0 = vd0 > 1.0f, s1 = vd1 > 1.0f;
        v3a = s0 ? 0.0f : vd0;
        v3b = s1 ? 0.0f : vd1;
        sum0 += s0 ? 1.0f : 0.0f;
        sum1 += s1 ? 1.0f : 0.0f;
        if (lane == 0)
            *(float2*)(outv + (size_t)t * 2 * B + 2 * sG) = make_float2(v3a, v3b);
    }

    if (lane == 0)
        *(float2*)(out + (size_t)2 * sG) = make_float2(sum0, sum1);
}

extern "C" void kernel_launch(void* const* d_in, const int* in_sizes, int n_in,
                              void* d_out, int out_size, void* d_ws, size_t ws_size,
                              hipStream_t stream)
{
    const float* x  = (const float*)d_in[0];
    const float* w1 = (const float*)d_in[1];
    const float* b1 = (const float*)d_in[2];
    const float* w2 = (const float*)d_in[3];
    const float* b2 = (const float*)d_in[4];
    const float* wf = (const float*)d_in[5];
    const float* bf = (const float*)d_in[6];
    float* out = (float*)d_out;

    const int B = in_sizes[0] / 256;     // x is [B,1,16,16]
    const int grid = B / 4;              // 4 samples per block

    hipLaunchKernelGGL(snn_kernel, dim3(grid), dim3(256), 0, stream,
                       x, w1, b1, w2, b2, wf, bf, out, B);
}